// Round 1
// baseline (170.303 us; speedup 1.0000x reference)
//
#include <hip/hip_runtime.h>

// HardNetLoss: a = x[:8192], p = x[8192:], d_ij = sqrt((1 - a_i·p_j + 1e-6)*2)
// pos_i = d_ii ; neg_i = min( min_{j!=i} d_ji , min_{j!=i} d_ij )
// out = mean( relu(1 - neg + pos) )
//
// Fused design: bf16 MFMA GEMM tiles (128x128, BK=64) compute d on the fly;
// per-wave shfl min-reduce -> per-block LDS min -> global atomicMin (uint bits,
// valid since d >= 0). dmat never materialized. ws usage: 96 KB.

#define CNT   8192
#define KDIM  256
#define BM    128
#define BN    128
#define BK    64
#define KST   (BK + 8)       // padded LDS k-stride (bf16 elems): bank-shift 4/row
#define BIGF  3.0e38f

typedef __bf16 bf16x8 __attribute__((ext_vector_type(8)));
typedef float  f32x4  __attribute__((ext_vector_type(4)));

__device__ __forceinline__ unsigned short f2bf(float f) {
    unsigned u = __float_as_uint(f);
    u += 0x7FFFu + ((u >> 16) & 1u);          // round-to-nearest-even
    return (unsigned short)(u >> 16);
}

__global__ __launch_bounds__(256) void init_min_kernel(unsigned* buf, int n) {
    int i = blockIdx.x * 256 + threadIdx.x;
    if (i < n) buf[i] = 0x7F7FFFFFu;          // FLT_MAX bits
}

__global__ __launch_bounds__(256) void dist_tile_kernel(
    const float* __restrict__ A, const float* __restrict__ P,
    unsigned* __restrict__ g_rowmin, unsigned* __restrict__ g_colmin,
    float* __restrict__ g_pos)
{
    __shared__ unsigned short As[BM * KST];   // 18432 B
    __shared__ unsigned short Bs[BN * KST];   // 18432 B
    __shared__ unsigned redrow[BM];
    __shared__ unsigned redcol[BN];

    const int tid  = threadIdx.x;
    const int bm   = blockIdx.y;
    const int bn   = blockIdx.x;
    const int wave = tid >> 6;
    const int lane = tid & 63;
    const int quad = lane >> 4;
    const int l15  = lane & 15;
    const int m_off = (wave >> 1) * 64;       // wave quadrant within 128x128 tile
    const int n_off = (wave & 1) * 64;

    if (tid < BM) redrow[tid] = 0x7F7FFFFFu;
    if (tid < BN) redcol[tid] = 0x7F7FFFFFu;

    const f32x4 fzero = {0.f, 0.f, 0.f, 0.f};
    f32x4 acc[4][4];
    #pragma unroll
    for (int i = 0; i < 4; i++)
        #pragma unroll
        for (int j = 0; j < 4; j++)
            acc[i][j] = fzero;

    const int srow = tid >> 4;                // 0..15: staging row group
    const int scol = tid & 15;                // float4 index within BK

    for (int kc = 0; kc < KDIM / BK; kc++) {
        // ---- stage A,B k-chunk into LDS as bf16 (coalesced float4 + convert)
        #pragma unroll
        for (int i = 0; i < 8; i++) {
            int r = srow + i * 16;
            float4 va = *(const float4*)(A + (size_t)(bm * BM + r) * KDIM + kc * BK + scol * 4);
            float4 vb = *(const float4*)(P + (size_t)(bn * BN + r) * KDIM + kc * BK + scol * 4);
            ushort4 wa, wb;
            wa.x = f2bf(va.x); wa.y = f2bf(va.y); wa.z = f2bf(va.z); wa.w = f2bf(va.w);
            wb.x = f2bf(vb.x); wb.y = f2bf(vb.y); wb.z = f2bf(vb.z); wb.w = f2bf(vb.w);
            *(ushort4*)(&As[r * KST + scol * 4]) = wa;
            *(ushort4*)(&Bs[r * KST + scol * 4]) = wb;
        }
        __syncthreads();

        // ---- MFMA: A frag m=lane&15,k=quad*8+j ; B frag n=lane&15,k=quad*8+j
        #pragma unroll
        for (int ks = 0; ks < BK / 32; ks++) {
            bf16x8 af[4], bfr[4];
            #pragma unroll
            for (int mi = 0; mi < 4; mi++) {
                uint4 u = *(const uint4*)(&As[(m_off + mi * 16 + l15) * KST + ks * 32 + quad * 8]);
                af[mi] = __builtin_bit_cast(bf16x8, u);
            }
            #pragma unroll
            for (int ni = 0; ni < 4; ni++) {
                uint4 u = *(const uint4*)(&Bs[(n_off + ni * 16 + l15) * KST + ks * 32 + quad * 8]);
                bfr[ni] = __builtin_bit_cast(bf16x8, u);
            }
            #pragma unroll
            for (int mi = 0; mi < 4; mi++)
                #pragma unroll
                for (int ni = 0; ni < 4; ni++)
                    acc[mi][ni] = __builtin_amdgcn_mfma_f32_16x16x32_bf16(
                        af[mi], bfr[ni], acc[mi][ni], 0, 0, 0);
        }
        __syncthreads();
    }

    // ---- epilogue: d = sqrt((1-s+eps)*2); diag -> pos; mins exclude diag
    // C/D layout: col = lane&15, row = quad*4 + reg  (guide m89/m91)
    float rmin[4][4];
    float cmin[4];
    #pragma unroll
    for (int mi = 0; mi < 4; mi++)
        #pragma unroll
        for (int r = 0; r < 4; r++)
            rmin[mi][r] = BIGF;
    #pragma unroll
    for (int ni = 0; ni < 4; ni++) cmin[ni] = BIGF;

    const int grow0 = bm * BM + m_off + quad * 4;
    const int gcol0 = bn * BN + n_off + l15;

    #pragma unroll
    for (int mi = 0; mi < 4; mi++) {
        #pragma unroll
        for (int ni = 0; ni < 4; ni++) {
            int gcol = gcol0 + ni * 16;
            #pragma unroll
            for (int r = 0; r < 4; r++) {
                int grow = grow0 + mi * 16 + r;
                float s = acc[mi][ni][r];
                float d = sqrtf((1.0f - s + 1e-6f) * 2.0f);
                float dm = d;
                if (grow == gcol) { g_pos[grow] = d; dm = BIGF; }
                rmin[mi][r] = fminf(rmin[mi][r], dm);
                cmin[ni]    = fminf(cmin[ni], dm);
            }
        }
    }

    // row mins: reduce across the 16 lanes of each quad (cols)
    #pragma unroll
    for (int mi = 0; mi < 4; mi++)
        #pragma unroll
        for (int r = 0; r < 4; r++) {
            float v = rmin[mi][r];
            v = fminf(v, __shfl_xor(v, 1, 64));
            v = fminf(v, __shfl_xor(v, 2, 64));
            v = fminf(v, __shfl_xor(v, 4, 64));
            v = fminf(v, __shfl_xor(v, 8, 64));
            rmin[mi][r] = v;
        }
    // col mins: reduce across the 4 quads (rows)
    #pragma unroll
    for (int ni = 0; ni < 4; ni++) {
        float v = cmin[ni];
        v = fminf(v, __shfl_xor(v, 16, 64));
        v = fminf(v, __shfl_xor(v, 32, 64));
        cmin[ni] = v;
    }

    if (l15 == 0) {
        #pragma unroll
        for (int mi = 0; mi < 4; mi++)
            #pragma unroll
            for (int r = 0; r < 4; r++)
                atomicMin(&redrow[m_off + mi * 16 + quad * 4 + r],
                          __float_as_uint(rmin[mi][r]));
    }
    if (quad == 0) {
        #pragma unroll
        for (int ni = 0; ni < 4; ni++)
            atomicMin(&redcol[n_off + ni * 16 + l15], __float_as_uint(cmin[ni]));
    }
    __syncthreads();

    if (tid < 128)      atomicMin(&g_rowmin[bm * BM + tid], redrow[tid]);
    else                atomicMin(&g_colmin[bn * BN + (tid - 128)], redcol[tid - 128]);
}

__global__ __launch_bounds__(1024) void finalize_kernel(
    const unsigned* __restrict__ g_rowmin, const unsigned* __restrict__ g_colmin,
    const float* __restrict__ g_pos, float* __restrict__ out)
{
    float local = 0.f;
    for (int i = threadIdx.x; i < CNT; i += 1024) {
        float neg = fminf(__uint_as_float(g_rowmin[i]), __uint_as_float(g_colmin[i]));
        float v = 1.0f - neg + g_pos[i];
        local += fmaxf(v, 0.0f);
    }
    #pragma unroll
    for (int m = 1; m < 64; m <<= 1) local += __shfl_xor(local, m, 64);
    __shared__ float wsum[16];
    if ((threadIdx.x & 63) == 0) wsum[threadIdx.x >> 6] = local;
    __syncthreads();
    if (threadIdx.x == 0) {
        float s = 0.f;
        #pragma unroll
        for (int w = 0; w < 16; w++) s += wsum[w];
        out[0] = s * (1.0f / (float)CNT);
    }
}

extern "C" void kernel_launch(void* const* d_in, const int* in_sizes, int n_in,
                              void* d_out, int out_size, void* d_ws, size_t ws_size,
                              hipStream_t stream) {
    const float* x = (const float*)d_in[0];
    const float* A = x;                              // [8192][256]
    const float* P = x + (size_t)CNT * KDIM;         // [8192][256]

    unsigned* rowmin = (unsigned*)d_ws;              // [8192] uint (float bits)
    unsigned* colmin = rowmin + CNT;                 // [8192]
    float*    pos    = (float*)(colmin + CNT);       // [8192]
    float*    out    = (float*)d_out;

    init_min_kernel<<<dim3(2 * CNT / 256), dim3(256), 0, stream>>>(rowmin, 2 * CNT);
    dist_tile_kernel<<<dim3(CNT / BN, CNT / BM), dim3(256), 0, stream>>>(
        A, P, rowmin, colmin, pos);
    finalize_kernel<<<dim3(1), dim3(1024), 0, stream>>>(rowmin, colmin, pos, out);
}

// Round 2
// 117.465 us; speedup vs baseline: 1.4498x; 1.4498x over previous
//
#include <hip/hip_runtime.h>

// HardNetLoss: a = x[:8192], p = x[8192:], d_ij = sqrt((1 - a_i·p_j + 1e-6)*2)
// pos_i = d_ii ; neg_i = min(min_{j!=i} d_ji, min_{j!=i} d_ij)
// out = mean(relu(1 - neg + pos))
//
// Fast path (needs ~8.5 MB ws): pre-convert x -> bf16 (XOR-swizzled chunk
// layout) once; 128x128 MFMA tiles staged via global_load_lds width=16;
// epilogue reduces max(s) (sqrt deferred to finalize, monotone transform).
// Fallback path (96 KB ws): round-1 kernel, known passing.

#define CNT   8192
#define KDIM  256
#define BIGF  3.0e38f

typedef __bf16 bf16x8 __attribute__((ext_vector_type(8)));
typedef float  f32x4  __attribute__((ext_vector_type(4)));

__device__ __forceinline__ unsigned short f2bf(float f) {
    unsigned u = __float_as_uint(f);
    u += 0x7FFFu + ((u >> 16) & 1u);          // round-to-nearest-even
    return (unsigned short)(u >> 16);
}

__device__ __forceinline__ void async16(const void* g, void* l) {
    __builtin_amdgcn_global_load_lds(
        (const __attribute__((address_space(1))) unsigned int*)g,
        (__attribute__((address_space(3))) unsigned int*)l,
        16, 0, 0);
}

// ---------------- fast path ----------------

// x fp32 [16384][256] -> xb bf16, chunk q (8 elems) of each row stored at
// slot q^(row&7) within its 64-col kc-group. Also inits the 16384 min slots.
__global__ __launch_bounds__(256) void convert_init_kernel(
    const float* __restrict__ x, unsigned short* __restrict__ xb,
    unsigned* __restrict__ mins)
{
    int t = blockIdx.x * 256 + threadIdx.x;   // 524288 threads, 8 elems each
    int elem = t * 8;
    int row  = elem >> 8;
    int col  = elem & 255;
    int q    = (col >> 3) & 7;
    int qs   = q ^ (row & 7);
    float4 v0 = *(const float4*)(x + elem);
    float4 v1 = *(const float4*)(x + elem + 4);
    ushort4 w0, w1;
    w0.x = f2bf(v0.x); w0.y = f2bf(v0.y); w0.z = f2bf(v0.z); w0.w = f2bf(v0.w);
    w1.x = f2bf(v1.x); w1.y = f2bf(v1.y); w1.z = f2bf(v1.z); w1.w = f2bf(v1.w);
    unsigned short* dst = xb + (row << 8) + (col & ~63) + qs * 8;
    *(ushort4*)dst       = w0;
    *(ushort4*)(dst + 4) = w1;
    if (t < 2 * CNT) mins[t] = 0x7F7FFFFFu;   // FLT_MAX bits
}

__global__ __launch_bounds__(256) void dist_bf16_kernel(
    const unsigned short* __restrict__ Ab, const unsigned short* __restrict__ Pb,
    unsigned* __restrict__ g_rowmin, unsigned* __restrict__ g_colmin,
    float* __restrict__ g_pos)
{
    __shared__ unsigned short As[128 * 64];   // 16 KB, unpadded (swizzled)
    __shared__ unsigned short Bs[128 * 64];   // 16 KB
    __shared__ unsigned redrow[128];
    __shared__ unsigned redcol[128];

    const int tid  = threadIdx.x;
    const int bm   = blockIdx.y;
    const int bn   = blockIdx.x;
    const int wave = tid >> 6;
    const int lane = tid & 63;
    const int quad = lane >> 4;
    const int l15  = lane & 15;
    const int m_off = (wave >> 1) * 64;
    const int n_off = (wave & 1) * 64;

    if (tid < 128) { redrow[tid] = 0x7F7FFFFFu; redcol[tid] = 0x7F7FFFFFu; }

    f32x4 acc[4][4];
    #pragma unroll
    for (int i = 0; i < 4; i++)
        #pragma unroll
        for (int j = 0; j < 4; j++)
            acc[i][j] = (f32x4){0.f, 0.f, 0.f, 0.f};

    // fragment LDS byte offsets (kc-invariant): chunk c of row r lives at
    // r*128 + (c ^ (r&7))*16, c = ks*4 + quad
    int a_off[4][2], b_off[4][2];
    #pragma unroll
    for (int i = 0; i < 4; i++) {
        int ra = m_off + i * 16 + l15;
        int rb = n_off + i * 16 + l15;
        #pragma unroll
        for (int ks = 0; ks < 2; ks++) {
            a_off[i][ks] = ra * 128 + (((ks * 4 + quad) ^ (ra & 7)) * 16);
            b_off[i][ks] = rb * 128 + (((ks * 4 + quad) ^ (rb & 7)) * 16);
        }
    }

    const int srow8 = lane >> 3;              // row within 8-row group
    const int sq    = lane & 7;               // 16B slot within 128B row-chunk

    #pragma unroll
    for (int kc = 0; kc < 4; kc++) {
        #pragma unroll
        for (int g = 0; g < 4; g++) {
            int r0 = (wave * 4 + g) * 8;
            async16(Ab + (size_t)(bm * 128 + r0 + srow8) * 256 + kc * 64 + sq * 8,
                    &As[r0 * 64]);
            async16(Pb + (size_t)(bn * 128 + r0 + srow8) * 256 + kc * 64 + sq * 8,
                    &Bs[r0 * 64]);
        }
        __syncthreads();
        #pragma unroll
        for (int ks = 0; ks < 2; ks++) {
            bf16x8 af[4], bfr[4];
            #pragma unroll
            for (int i = 0; i < 4; i++)
                af[i] = *(const bf16x8*)((const char*)As + a_off[i][ks]);
            #pragma unroll
            for (int i = 0; i < 4; i++)
                bfr[i] = *(const bf16x8*)((const char*)Bs + b_off[i][ks]);
            #pragma unroll
            for (int mi = 0; mi < 4; mi++)
                #pragma unroll
                for (int ni = 0; ni < 4; ni++)
                    acc[mi][ni] = __builtin_amdgcn_mfma_f32_16x16x32_bf16(
                        af[mi], bfr[ni], acc[mi][ni], 0, 0, 0);
        }
        __syncthreads();
    }

    // epilogue: reduce MAX(s); min d = sqrt((1 - max s + eps)*2) by monotonicity
    // C/D layout: col = lane&15, row = quad*4 + reg
    float rmax[4][4], cmax[4];
    #pragma unroll
    for (int mi = 0; mi < 4; mi++)
        #pragma unroll
        for (int r = 0; r < 4; r++) rmax[mi][r] = -BIGF;
    #pragma unroll
    for (int ni = 0; ni < 4; ni++) cmax[ni] = -BIGF;

    const int lr0 = m_off + quad * 4;
    const int lc0 = n_off + l15;

    if (bm == bn) {
        #pragma unroll
        for (int mi = 0; mi < 4; mi++)
            #pragma unroll
            for (int ni = 0; ni < 4; ni++)
                #pragma unroll
                for (int r = 0; r < 4; r++) {
                    float s = acc[mi][ni][r];
                    if (lr0 + mi * 16 + r == lc0 + ni * 16) {
                        g_pos[bm * 128 + lr0 + mi * 16 + r] = (1.0f - s + 1e-6f) * 2.0f;
                        s = -BIGF;
                    }
                    rmax[mi][r] = fmaxf(rmax[mi][r], s);
                    cmax[ni]    = fmaxf(cmax[ni], s);
                }
    } else {
        #pragma unroll
        for (int mi = 0; mi < 4; mi++)
            #pragma unroll
            for (int ni = 0; ni < 4; ni++)
                #pragma unroll
                for (int r = 0; r < 4; r++) {
                    float s = acc[mi][ni][r];
                    rmax[mi][r] = fmaxf(rmax[mi][r], s);
                    cmax[ni]    = fmaxf(cmax[ni], s);
                }
    }

    #pragma unroll
    for (int mi = 0; mi < 4; mi++)
        #pragma unroll
        for (int r = 0; r < 4; r++) {
            float v = rmax[mi][r];
            v = fmaxf(v, __shfl_xor(v, 1, 64));
            v = fmaxf(v, __shfl_xor(v, 2, 64));
            v = fmaxf(v, __shfl_xor(v, 4, 64));
            v = fmaxf(v, __shfl_xor(v, 8, 64));
            rmax[mi][r] = v;
        }
    #pragma unroll
    for (int ni = 0; ni < 4; ni++) {
        float v = cmax[ni];
        v = fmaxf(v, __shfl_xor(v, 16, 64));
        v = fmaxf(v, __shfl_xor(v, 32, 64));
        cmax[ni] = v;
    }

    if (l15 == 0) {
        #pragma unroll
        for (int mi = 0; mi < 4; mi++)
            #pragma unroll
            for (int r = 0; r < 4; r++) {
                float t = (1.0f - rmax[mi][r] + 1e-6f) * 2.0f;
                atomicMin(&redrow[m_off + mi * 16 + quad * 4 + r],
                          __float_as_uint(fmaxf(t, 0.f)));
            }
    }
    if (quad == 0) {
        #pragma unroll
        for (int ni = 0; ni < 4; ni++) {
            float t = (1.0f - cmax[ni] + 1e-6f) * 2.0f;
            atomicMin(&redcol[n_off + ni * 16 + l15], __float_as_uint(fmaxf(t, 0.f)));
        }
    }
    __syncthreads();

    if (tid < 128) atomicMin(&g_rowmin[bm * 128 + tid], redrow[tid]);
    else           atomicMin(&g_colmin[bn * 128 + tid - 128], redcol[tid - 128]);
}

__global__ __launch_bounds__(1024) void finalize_t_kernel(
    const unsigned* __restrict__ rm, const unsigned* __restrict__ cm,
    const float* __restrict__ post, float* __restrict__ out)
{
    float local = 0.f;
    for (int i = threadIdx.x; i < CNT; i += 1024) {
        float t   = fminf(__uint_as_float(rm[i]), __uint_as_float(cm[i]));
        float neg = sqrtf(fmaxf(t, 0.f));
        float pos = sqrtf(fmaxf(post[i], 0.f));
        local += fmaxf(1.0f - neg + pos, 0.0f);
    }
    #pragma unroll
    for (int m = 1; m < 64; m <<= 1) local += __shfl_xor(local, m, 64);
    __shared__ float wsum[16];
    if ((threadIdx.x & 63) == 0) wsum[threadIdx.x >> 6] = local;
    __syncthreads();
    if (threadIdx.x == 0) {
        float s = 0.f;
        #pragma unroll
        for (int w = 0; w < 16; w++) s += wsum[w];
        out[0] = s * (1.0f / (float)CNT);
    }
}

// ---------------- fallback path (round-1, known passing; 96 KB ws) ----------------

#define BM 128
#define BN 128
#define BK 64
#define KST (BK + 8)

__global__ __launch_bounds__(256) void init_min_kernel(unsigned* buf, int n) {
    int i = blockIdx.x * 256 + threadIdx.x;
    if (i < n) buf[i] = 0x7F7FFFFFu;
}

__global__ __launch_bounds__(256) void dist_tile_kernel(
    const float* __restrict__ A, const float* __restrict__ P,
    unsigned* __restrict__ g_rowmin, unsigned* __restrict__ g_colmin,
    float* __restrict__ g_pos)
{
    __shared__ unsigned short As[BM * KST];
    __shared__ unsigned short Bs[BN * KST];
    __shared__ unsigned redrow[BM];
    __shared__ unsigned redcol[BN];

    const int tid  = threadIdx.x;
    const int bm   = blockIdx.y;
    const int bn   = blockIdx.x;
    const int wave = tid >> 6;
    const int lane = tid & 63;
    const int quad = lane >> 4;
    const int l15  = lane & 15;
    const int m_off = (wave >> 1) * 64;
    const int n_off = (wave & 1) * 64;

    if (tid < BM) redrow[tid] = 0x7F7FFFFFu;
    if (tid < BN) redcol[tid] = 0x7F7FFFFFu;

    f32x4 acc[4][4];
    #pragma unroll
    for (int i = 0; i < 4; i++)
        #pragma unroll
        for (int j = 0; j < 4; j++)
            acc[i][j] = (f32x4){0.f, 0.f, 0.f, 0.f};

    const int srow = tid >> 4;
    const int scol = tid & 15;

    for (int kc = 0; kc < KDIM / BK; kc++) {
        #pragma unroll
        for (int i = 0; i < 8; i++) {
            int r = srow + i * 16;
            float4 va = *(const float4*)(A + (size_t)(bm * BM + r) * KDIM + kc * BK + scol * 4);
            float4 vb = *(const float4*)(P + (size_t)(bn * BN + r) * KDIM + kc * BK + scol * 4);
            ushort4 wa, wb;
            wa.x = f2bf(va.x); wa.y = f2bf(va.y); wa.z = f2bf(va.z); wa.w = f2bf(va.w);
            wb.x = f2bf(vb.x); wb.y = f2bf(vb.y); wb.z = f2bf(vb.z); wb.w = f2bf(vb.w);
            *(ushort4*)(&As[r * KST + scol * 4]) = wa;
            *(ushort4*)(&Bs[r * KST + scol * 4]) = wb;
        }
        __syncthreads();
        #pragma unroll
        for (int ks = 0; ks < BK / 32; ks++) {
            bf16x8 af[4], bfr[4];
            #pragma unroll
            for (int mi = 0; mi < 4; mi++)
                af[mi] = *(const bf16x8*)(&As[(m_off + mi * 16 + l15) * KST + ks * 32 + quad * 8]);
            #pragma unroll
            for (int ni = 0; ni < 4; ni++)
                bfr[ni] = *(const bf16x8*)(&Bs[(n_off + ni * 16 + l15) * KST + ks * 32 + quad * 8]);
            #pragma unroll
            for (int mi = 0; mi < 4; mi++)
                #pragma unroll
                for (int ni = 0; ni < 4; ni++)
                    acc[mi][ni] = __builtin_amdgcn_mfma_f32_16x16x32_bf16(
                        af[mi], bfr[ni], acc[mi][ni], 0, 0, 0);
        }
        __syncthreads();
    }

    float rmin[4][4], cmin[4];
    #pragma unroll
    for (int mi = 0; mi < 4; mi++)
        #pragma unroll
        for (int r = 0; r < 4; r++) rmin[mi][r] = BIGF;
    #pragma unroll
    for (int ni = 0; ni < 4; ni++) cmin[ni] = BIGF;

    const int grow0 = bm * BM + m_off + quad * 4;
    const int gcol0 = bn * BN + n_off + l15;

    #pragma unroll
    for (int mi = 0; mi < 4; mi++)
        #pragma unroll
        for (int ni = 0; ni < 4; ni++) {
            int gcol = gcol0 + ni * 16;
            #pragma unroll
            for (int r = 0; r < 4; r++) {
                int grow = grow0 + mi * 16 + r;
                float s = acc[mi][ni][r];
                float d = sqrtf((1.0f - s + 1e-6f) * 2.0f);
                float dm = d;
                if (grow == gcol) { g_pos[grow] = d; dm = BIGF; }
                rmin[mi][r] = fminf(rmin[mi][r], dm);
                cmin[ni]    = fminf(cmin[ni], dm);
            }
        }

    #pragma unroll
    for (int mi = 0; mi < 4; mi++)
        #pragma unroll
        for (int r = 0; r < 4; r++) {
            float v = rmin[mi][r];
            v = fminf(v, __shfl_xor(v, 1, 64));
            v = fminf(v, __shfl_xor(v, 2, 64));
            v = fminf(v, __shfl_xor(v, 4, 64));
            v = fminf(v, __shfl_xor(v, 8, 64));
            rmin[mi][r] = v;
        }
    #pragma unroll
    for (int ni = 0; ni < 4; ni++) {
        float v = cmin[ni];
        v = fminf(v, __shfl_xor(v, 16, 64));
        v = fminf(v, __shfl_xor(v, 32, 64));
        cmin[ni] = v;
    }

    if (l15 == 0) {
        #pragma unroll
        for (int mi = 0; mi < 4; mi++)
            #pragma unroll
            for (int r = 0; r < 4; r++)
                atomicMin(&redrow[m_off + mi * 16 + quad * 4 + r],
                          __float_as_uint(rmin[mi][r]));
    }
    if (quad == 0) {
        #pragma unroll
        for (int ni = 0; ni < 4; ni++)
            atomicMin(&redcol[n_off + ni * 16 + l15], __float_as_uint(cmin[ni]));
    }
    __syncthreads();

    if (tid < 128) atomicMin(&g_rowmin[bm * BM + tid], redrow[tid]);
    else           atomicMin(&g_colmin[bn * BN + (tid - 128)], redcol[tid - 128]);
}

__global__ __launch_bounds__(1024) void finalize_kernel(
    const unsigned* __restrict__ g_rowmin, const unsigned* __restrict__ g_colmin,
    const float* __restrict__ g_pos, float* __restrict__ out)
{
    float local = 0.f;
    for (int i = threadIdx.x; i < CNT; i += 1024) {
        float neg = fminf(__uint_as_float(g_rowmin[i]), __uint_as_float(g_colmin[i]));
        float v = 1.0f - neg + g_pos[i];
        local += fmaxf(v, 0.0f);
    }
    #pragma unroll
    for (int m = 1; m < 64; m <<= 1) local += __shfl_xor(local, m, 64);
    __shared__ float wsum[16];
    if ((threadIdx.x & 63) == 0) wsum[threadIdx.x >> 6] = local;
    __syncthreads();
    if (threadIdx.x == 0) {
        float s = 0.f;
        #pragma unroll
        for (int w = 0; w < 16; w++) s += wsum[w];
        out[0] = s * (1.0f / (float)CNT);
    }
}

// ---------------- host ----------------

extern "C" void kernel_launch(void* const* d_in, const int* in_sizes, int n_in,
                              void* d_out, int out_size, void* d_ws, size_t ws_size,
                              hipStream_t stream) {
    const float* x = (const float*)d_in[0];
    float* out = (float*)d_out;

    const size_t bf16_bytes = (size_t)2 * CNT * KDIM * 2;   // 8,388,608
    const size_t need = bf16_bytes + (size_t)2 * CNT * 4 + (size_t)CNT * 4;

    if (ws_size >= need) {
        unsigned short* xb   = (unsigned short*)d_ws;
        unsigned*       mins = (unsigned*)((char*)d_ws + bf16_bytes);
        float*          pos  = (float*)(mins + 2 * CNT);
        convert_init_kernel<<<dim3(2048), dim3(256), 0, stream>>>(x, xb, mins);
        dist_bf16_kernel<<<dim3(64, 64), dim3(256), 0, stream>>>(
            xb, xb + (size_t)CNT * KDIM, mins, mins + CNT, pos);
        finalize_t_kernel<<<dim3(1), dim3(1024), 0, stream>>>(mins, mins + CNT, pos, out);
    } else {
        unsigned* rowmin = (unsigned*)d_ws;
        unsigned* colmin = rowmin + CNT;
        float*    pos    = (float*)(colmin + CNT);
        init_min_kernel<<<dim3(2 * CNT / 256), dim3(256), 0, stream>>>(rowmin, 2 * CNT);
        dist_tile_kernel<<<dim3(CNT / BN, CNT / BM), dim3(256), 0, stream>>>(
            x, x + (size_t)CNT * KDIM, rowmin, colmin, pos);
        finalize_kernel<<<dim3(1), dim3(1024), 0, stream>>>(rowmin, colmin, pos, out);
    }
}

// Round 3
// 106.030 us; speedup vs baseline: 1.6062x; 1.1079x over previous
//
#include <hip/hip_runtime.h>

// HardNetLoss: a = x[:8192], p = x[8192:], d_ij = sqrt((1 - a_i·p_j + 1e-6)*2)
// pos_i = d_ii ; neg_i = min(min_{j!=i} d_ji, min_{j!=i} d_ij)
// out = mean(relu(1 - neg + pos))
//
// R3: DS-pipe was the bottleneck (frag reads + shuffle epilogue). Now:
// 128x256 block tile (wave tile 64x128, acc 128 VGPR) cuts frag bytes 25%;
// row-min reduction via LDS transpose (b128 writes + strided b32 reads)
// replaces the 128-shuffle butterfly; XCD-aware block swizzle keeps each
// XCD's staging traffic (3 MB) L2-resident.

#define CNT   8192
#define KDIM  256
#define BIGF  3.0e38f

typedef __bf16 bf16x8 __attribute__((ext_vector_type(8)));
typedef float  f32x4  __attribute__((ext_vector_type(4)));

__device__ __forceinline__ unsigned short f2bf(float f) {
    unsigned u = __float_as_uint(f);
    u += 0x7FFFu + ((u >> 16) & 1u);          // round-to-nearest-even
    return (unsigned short)(u >> 16);
}

__device__ __forceinline__ void async16(const void* g, void* l) {
    __builtin_amdgcn_global_load_lds(
        (const __attribute__((address_space(1))) unsigned int*)g,
        (__attribute__((address_space(3))) unsigned int*)l,
        16, 0, 0);
}

// ---------------- fast path ----------------

// x fp32 [16384][256] -> xb bf16, chunk q (8 elems) of each row stored at
// slot q^(row&7) within its 64-col kc-group. Also inits the 16384 min slots.
__global__ __launch_bounds__(256) void convert_init_kernel(
    const float* __restrict__ x, unsigned short* __restrict__ xb,
    unsigned* __restrict__ mins)
{
    int t = blockIdx.x * 256 + threadIdx.x;   // 524288 threads, 8 elems each
    int elem = t * 8;
    int row  = elem >> 8;
    int col  = elem & 255;
    int q    = (col >> 3) & 7;
    int qs   = q ^ (row & 7);
    float4 v0 = *(const float4*)(x + elem);
    float4 v1 = *(const float4*)(x + elem + 4);
    uint4 w;
    w.x = (unsigned)f2bf(v0.x) | ((unsigned)f2bf(v0.y) << 16);
    w.y = (unsigned)f2bf(v0.z) | ((unsigned)f2bf(v0.w) << 16);
    w.z = (unsigned)f2bf(v1.x) | ((unsigned)f2bf(v1.y) << 16);
    w.w = (unsigned)f2bf(v1.z) | ((unsigned)f2bf(v1.w) << 16);
    *(uint4*)(xb + (row << 8) + (col & ~63) + qs * 8) = w;
    if (t < 2 * CNT) mins[t] = 0x7F7FFFFFu;   // FLT_MAX bits
}

// block tile 128(m) x 256(n); 4 waves 2x2; wave tile 64x128 of 16x16x32 MFMA.
#define TST 132                                // T leading stride (f32), 16B-aligned
__global__ __launch_bounds__(256, 2) void dist3_kernel(
    const unsigned short* __restrict__ Ab, const unsigned short* __restrict__ Pb,
    unsigned* __restrict__ g_rowmin, unsigned* __restrict__ g_colmin,
    float* __restrict__ g_pos)
{
    __shared__ unsigned short As[128 * 64];   // 16 KB
    __shared__ unsigned short Bs[256 * 64];   // 32 KB; T aliases this post-loop
    float* T = (float*)Bs;                    // [32][TST] = 16.9 KB

    const int tid  = threadIdx.x;
    // XCD-aware swizzle: 8 regions of 16x16 blocks (1MB A + 2MB P per XCD L2)
    const int l    = blockIdx.x;
    const int xcd  = l & 7;
    const int i    = l >> 3;                  // 0..255
    const int bm   = (xcd >> 1) * 16 + (i & 15);   // 0..63
    const int bn   = (xcd & 1) * 16 + (i >> 4);    // 0..31

    const int wave = tid >> 6;
    const int lane = tid & 63;
    const int quad = lane >> 4;
    const int l15  = lane & 15;
    const int wm   = wave >> 1;               // 0..1 : m half
    const int wn   = wave & 1;                // 0..1 : n half

    f32x4 acc[4][8];
    #pragma unroll
    for (int a = 0; a < 4; a++)
        #pragma unroll
        for (int b = 0; b < 8; b++)
            acc[a][b] = (f32x4){0.f, 0.f, 0.f, 0.f};

    // fragment LDS byte offsets (kc-invariant): row r chunk c at r*128 + (c^(r&7))*16
    int a_off[4][2], b_off[8][2];
    #pragma unroll
    for (int mi = 0; mi < 4; mi++) {
        int ra = wm * 64 + mi * 16 + l15;
        #pragma unroll
        for (int ks = 0; ks < 2; ks++)
            a_off[mi][ks] = ra * 128 + (((ks * 4 + quad) ^ (ra & 7)) * 16);
    }
    #pragma unroll
    for (int ni = 0; ni < 8; ni++) {
        int rb = wn * 128 + ni * 16 + l15;
        #pragma unroll
        for (int ks = 0; ks < 2; ks++)
            b_off[ni][ks] = rb * 128 + (((ks * 4 + quad) ^ (rb & 7)) * 16);
    }

    const int srow8 = lane >> 3;              // row within 8-row group
    const int sq    = lane & 7;               // 16B slot within 128B row-chunk

    #pragma unroll
    for (int kc = 0; kc < 4; kc++) {
        #pragma unroll
        for (int g = 0; g < 4; g++) {         // A: 128 rows = 4 waves x 4 groups x 8
            int r0 = wave * 32 + g * 8;
            async16(Ab + (size_t)(bm * 128 + r0 + srow8) * 256 + kc * 64 + sq * 8,
                    &As[r0 * 64]);
        }
        #pragma unroll
        for (int g = 0; g < 8; g++) {         // B: 256 rows = 4 waves x 8 groups x 8
            int r0 = wave * 64 + g * 8;
            async16(Pb + (size_t)(bn * 256 + r0 + srow8) * 256 + kc * 64 + sq * 8,
                    &Bs[r0 * 64]);
        }
        __syncthreads();
        #pragma unroll
        for (int ks = 0; ks < 2; ks++) {
            bf16x8 af[4], bfr[8];
            #pragma unroll
            for (int mi = 0; mi < 4; mi++)
                af[mi] = *(const bf16x8*)((const char*)As + a_off[mi][ks]);
            #pragma unroll
            for (int ni = 0; ni < 8; ni++)
                bfr[ni] = *(const bf16x8*)((const char*)Bs + b_off[ni][ks]);
            #pragma unroll
            for (int mi = 0; mi < 4; mi++)
                #pragma unroll
                for (int ni = 0; ni < 8; ni++)
                    acc[mi][ni] = __builtin_amdgcn_mfma_f32_16x16x32_bf16(
                        af[mi], bfr[ni], acc[mi][ni], 0, 0, 0);
        }
        __syncthreads();
    }

    // ---- epilogue. C/D layout: col = lane&15, row = quad*4 + reg (verified R2).
    // local row rl = wm*64 + mi*16 + quad*4 + r (0..127)
    // local col cl = wn*128 + ni*16 + l15      (0..255)

    // diagonal blocks: global row bm*128+rl == col bn*256+cl  <=>  (bm>>1)==bn
    if ((bm >> 1) == bn) {
        const int dstart = (bm & 1) * 128;
        #pragma unroll
        for (int mi = 0; mi < 4; mi++)
            #pragma unroll
            for (int ni = 0; ni < 8; ni++)
                #pragma unroll
                for (int r = 0; r < 4; r++) {
                    int rl = wm * 64 + mi * 16 + quad * 4 + r;
                    int cl = wn * 128 + ni * 16 + l15;
                    if (cl == rl + dstart) {
                        g_pos[bm * 128 + rl] = (1.0f - acc[mi][ni][r] + 1e-6f) * 2.0f;
                        acc[mi][ni][r] = -BIGF;
                    }
                }
    }

    // col-direction (min over rows, i.e. max s over m): in-lane + 2 quad shuffles
    #pragma unroll
    for (int ni = 0; ni < 8; ni++) {
        float v = -BIGF;
        #pragma unroll
        for (int mi = 0; mi < 4; mi++)
            #pragma unroll
            for (int r = 0; r < 4; r++)
                v = fmaxf(v, acc[mi][ni][r]);
        v = fmaxf(v, __shfl_xor(v, 16, 64));
        v = fmaxf(v, __shfl_xor(v, 32, 64));
        if (quad == 0) {
            float tt = fmaxf((1.0f - v + 1e-6f) * 2.0f, 0.0f);
            atomicMin(&g_colmin[bn * 256 + wn * 128 + ni * 16 + l15],
                      __float_as_uint(tt));
        }
    }

    // row-direction: fold over ni in-lane, then LDS transpose (r is contiguous)
    float rmax[4][4];
    #pragma unroll
    for (int mi = 0; mi < 4; mi++)
        #pragma unroll
        for (int r = 0; r < 4; r++) {
            float v = acc[mi][0][r];
            #pragma unroll
            for (int ni = 1; ni < 8; ni++) v = fmaxf(v, acc[mi][ni][r]);
            rmax[mi][r] = v;
        }
    __syncthreads();                          // K-loop's Bs use is done; reuse as T
    const int centry = wn * 16 + l15;         // 0..31
    #pragma unroll
    for (int mi = 0; mi < 4; mi++) {
        f32x4 v = {rmax[mi][0], rmax[mi][1], rmax[mi][2], rmax[mi][3]};
        *(f32x4*)&T[centry * TST + wm * 64 + mi * 16 + quad * 4] = v;
    }
    __syncthreads();

    if (tid < 128) {
        int row = tid;
        float v0 = T[row], v1 = T[TST + row];
        #pragma unroll
        for (int c = 2; c < 32; c += 2) {
            v0 = fmaxf(v0, T[c * TST + row]);
            v1 = fmaxf(v1, T[(c + 1) * TST + row]);
        }
        float v = fmaxf(v0, v1);
        float tt = fmaxf((1.0f - v + 1e-6f) * 2.0f, 0.0f);
        atomicMin(&g_rowmin[bm * 128 + row], __float_as_uint(tt));
    }
}

__global__ __launch_bounds__(1024) void finalize_t_kernel(
    const unsigned* __restrict__ rm, const unsigned* __restrict__ cm,
    const float* __restrict__ post, float* __restrict__ out)
{
    float local = 0.f;
    for (int i = threadIdx.x; i < CNT; i += 1024) {
        float t   = fminf(__uint_as_float(rm[i]), __uint_as_float(cm[i]));
        float neg = sqrtf(fmaxf(t, 0.f));
        float pos = sqrtf(fmaxf(post[i], 0.f));
        local += fmaxf(1.0f - neg + pos, 0.0f);
    }
    #pragma unroll
    for (int m = 1; m < 64; m <<= 1) local += __shfl_xor(local, m, 64);
    __shared__ float wsum[16];
    if ((threadIdx.x & 63) == 0) wsum[threadIdx.x >> 6] = local;
    __syncthreads();
    if (threadIdx.x == 0) {
        float s = 0.f;
        #pragma unroll
        for (int w = 0; w < 16; w++) s += wsum[w];
        out[0] = s * (1.0f / (float)CNT);
    }
}

// ---------------- fallback path (round-1, known passing; 96 KB ws) ----------------

#define BM 128
#define BN 128
#define BK 64
#define KST (BK + 8)

__global__ __launch_bounds__(256) void init_min_kernel(unsigned* buf, int n) {
    int i = blockIdx.x * 256 + threadIdx.x;
    if (i < n) buf[i] = 0x7F7FFFFFu;
}

__global__ __launch_bounds__(256) void dist_tile_kernel(
    const float* __restrict__ A, const float* __restrict__ P,
    unsigned* __restrict__ g_rowmin, unsigned* __restrict__ g_colmin,
    float* __restrict__ g_pos)
{
    __shared__ unsigned short As[BM * KST];
    __shared__ unsigned short Bs[BN * KST];
    __shared__ unsigned redrow[BM];
    __shared__ unsigned redcol[BN];

    const int tid  = threadIdx.x;
    const int bm   = blockIdx.y;
    const int bn   = blockIdx.x;
    const int wave = tid >> 6;
    const int lane = tid & 63;
    const int quad = lane >> 4;
    const int l15  = lane & 15;
    const int m_off = (wave >> 1) * 64;
    const int n_off = (wave & 1) * 64;

    if (tid < BM) redrow[tid] = 0x7F7FFFFFu;
    if (tid < BN) redcol[tid] = 0x7F7FFFFFu;

    f32x4 acc[4][4];
    #pragma unroll
    for (int i = 0; i < 4; i++)
        #pragma unroll
        for (int j = 0; j < 4; j++)
            acc[i][j] = (f32x4){0.f, 0.f, 0.f, 0.f};

    const int srow = tid >> 4;
    const int scol = tid & 15;

    for (int kc = 0; kc < KDIM / BK; kc++) {
        #pragma unroll
        for (int i = 0; i < 8; i++) {
            int r = srow + i * 16;
            float4 va = *(const float4*)(A + (size_t)(bm * BM + r) * KDIM + kc * BK + scol * 4);
            float4 vb = *(const float4*)(P + (size_t)(bn * BN + r) * KDIM + kc * BK + scol * 4);
            ushort4 wa, wb;
            wa.x = f2bf(va.x); wa.y = f2bf(va.y); wa.z = f2bf(va.z); wa.w = f2bf(va.w);
            wb.x = f2bf(vb.x); wb.y = f2bf(vb.y); wb.z = f2bf(vb.z); wb.w = f2bf(vb.w);
            *(ushort4*)(&As[r * KST + scol * 4]) = wa;
            *(ushort4*)(&Bs[r * KST + scol * 4]) = wb;
        }
        __syncthreads();
        #pragma unroll
        for (int ks = 0; ks < BK / 32; ks++) {
            bf16x8 af[4], bfr[4];
            #pragma unroll
            for (int mi = 0; mi < 4; mi++)
                af[mi] = *(const bf16x8*)(&As[(m_off + mi * 16 + l15) * KST + ks * 32 + quad * 8]);
            #pragma unroll
            for (int ni = 0; ni < 4; ni++)
                bfr[ni] = *(const bf16x8*)(&Bs[(n_off + ni * 16 + l15) * KST + ks * 32 + quad * 8]);
            #pragma unroll
            for (int mi = 0; mi < 4; mi++)
                #pragma unroll
                for (int ni = 0; ni < 4; ni++)
                    acc[mi][ni] = __builtin_amdgcn_mfma_f32_16x16x32_bf16(
                        af[mi], bfr[ni], acc[mi][ni], 0, 0, 0);
        }
        __syncthreads();
    }

    float rmin[4][4], cmin[4];
    #pragma unroll
    for (int mi = 0; mi < 4; mi++)
        #pragma unroll
        for (int r = 0; r < 4; r++) rmin[mi][r] = BIGF;
    #pragma unroll
    for (int ni = 0; ni < 4; ni++) cmin[ni] = BIGF;

    const int grow0 = bm * BM + m_off + quad * 4;
    const int gcol0 = bn * BN + n_off + l15;

    #pragma unroll
    for (int mi = 0; mi < 4; mi++)
        #pragma unroll
        for (int ni = 0; ni < 4; ni++) {
            int gcol = gcol0 + ni * 16;
            #pragma unroll
            for (int r = 0; r < 4; r++) {
                int grow = grow0 + mi * 16 + r;
                float s = acc[mi][ni][r];
                float d = sqrtf((1.0f - s + 1e-6f) * 2.0f);
                float dm = d;
                if (grow == gcol) { g_pos[grow] = d; dm = BIGF; }
                rmin[mi][r] = fminf(rmin[mi][r], dm);
                cmin[ni]    = fminf(cmin[ni], dm);
            }
        }

    #pragma unroll
    for (int mi = 0; mi < 4; mi++)
        #pragma unroll
        for (int r = 0; r < 4; r++) {
            float v = rmin[mi][r];
            v = fminf(v, __shfl_xor(v, 1, 64));
            v = fminf(v, __shfl_xor(v, 2, 64));
            v = fminf(v, __shfl_xor(v, 4, 64));
            v = fminf(v, __shfl_xor(v, 8, 64));
            rmin[mi][r] = v;
        }
    #pragma unroll
    for (int ni = 0; ni < 4; ni++) {
        float v = cmin[ni];
        v = fminf(v, __shfl_xor(v, 16, 64));
        v = fminf(v, __shfl_xor(v, 32, 64));
        cmin[ni] = v;
    }

    if (l15 == 0) {
        #pragma unroll
        for (int mi = 0; mi < 4; mi++)
            #pragma unroll
            for (int r = 0; r < 4; r++)
                atomicMin(&redrow[m_off + mi * 16 + quad * 4 + r],
                          __float_as_uint(rmin[mi][r]));
    }
    if (quad == 0) {
        #pragma unroll
        for (int ni = 0; ni < 4; ni++)
            atomicMin(&redcol[n_off + ni * 16 + l15], __float_as_uint(cmin[ni]));
    }
    __syncthreads();

    if (tid < 128) atomicMin(&g_rowmin[bm * BM + tid], redrow[tid]);
    else           atomicMin(&g_colmin[bn * BN + (tid - 128)], redcol[tid - 128]);
}

__global__ __launch_bounds__(1024) void finalize_kernel(
    const unsigned* __restrict__ g_rowmin, const unsigned* __restrict__ g_colmin,
    const float* __restrict__ g_pos, float* __restrict__ out)
{
    float local = 0.f;
    for (int i = threadIdx.x; i < CNT; i += 1024) {
        float neg = fminf(__uint_as_float(g_rowmin[i]), __uint_as_float(g_colmin[i]));
        float v = 1.0f - neg + g_pos[i];
        local += fmaxf(v, 0.0f);
    }
    #pragma unroll
    for (int m = 1; m < 64; m <<= 1) local += __shfl_xor(local, m, 64);
    __shared__ float wsum[16];
    if ((threadIdx.x & 63) == 0) wsum[threadIdx.x >> 6] = local;
    __syncthreads();
    if (threadIdx.x == 0) {
        float s = 0.f;
        #pragma unroll
        for (int w = 0; w < 16; w++) s += wsum[w];
        out[0] = s * (1.0f / (float)CNT);
    }
}

// ---------------- host ----------------

extern "C" void kernel_launch(void* const* d_in, const int* in_sizes, int n_in,
                              void* d_out, int out_size, void* d_ws, size_t ws_size,
                              hipStream_t stream) {
    const float* x = (const float*)d_in[0];
    float* out = (float*)d_out;

    const size_t bf16_bytes = (size_t)2 * CNT * KDIM * 2;   // 8,388,608
    const size_t need = bf16_bytes + (size_t)2 * CNT * 4 + (size_t)CNT * 4;

    if (ws_size >= need) {
        unsigned short* xb   = (unsigned short*)d_ws;
        unsigned*       mins = (unsigned*)((char*)d_ws + bf16_bytes);
        float*          pos  = (float*)(mins + 2 * CNT);
        convert_init_kernel<<<dim3(2048), dim3(256), 0, stream>>>(x, xb, mins);
        dist3_kernel<<<dim3(2048), dim3(256), 0, stream>>>(
            xb, xb + (size_t)CNT * KDIM, mins, mins + CNT, pos);
        finalize_t_kernel<<<dim3(1), dim3(1024), 0, stream>>>(mins, mins + CNT, pos, out);
    } else {
        unsigned* rowmin = (unsigned*)d_ws;
        unsigned* colmin = rowmin + CNT;
        float*    pos    = (float*)(colmin + CNT);
        init_min_kernel<<<dim3(2 * CNT / 256), dim3(256), 0, stream>>>(rowmin, 2 * CNT);
        dist_tile_kernel<<<dim3(CNT / BN, CNT / BM), dim3(256), 0, stream>>>(
            x, x + (size_t)CNT * KDIM, rowmin, colmin, pos);
        finalize_kernel<<<dim3(1), dim3(1024), 0, stream>>>(rowmin, colmin, pos, out);
    }
}